// Round 2
// baseline (1124.107 us; speedup 1.0000x reference)
//
#include <hip/hip_runtime.h>

#define HIDDEN 1152
#define IN_DIM 768
#define POS_SIZE 64
#define M_TOTAL (16 * 4096)

#define BM 64
#define KSTEPS 24          /* 768 / 32 */
#define LDA 776            /* LDS row stride in halves: 768 + 8 pad -> +16B/row bank rotation */

typedef _Float16 f16x8 __attribute__((ext_vector_type(8)));
typedef float f32x4 __attribute__((ext_vector_type(4)));
typedef float f32x8v __attribute__((ext_vector_type(8)));

// ---------------------------------------------------------------------------
// Pack W fp32 [1152][768] row-major -> f16, fragment-ordered so the gemm's
// per-wave B-fragment load is one fully-coalesced global_load_dwordx4:
//   chunk(n16, ks, quad, l15) at chunk index n16*1536 + ks*64 + quad*16 + l15
//   holds Wh[n16*16 + l15][ks*32 + quad*8 .. +8)   (8 halves = 16 B)
// Thread tid reads row-sequentially (coalesced): n = tid/96, kc = tid%96,
// ks = kc>>2, quad = kc&3  ->  dst chunk = n16*1536 + kc*16 + l15.
// ---------------------------------------------------------------------------
__global__ __launch_bounds__(256) void pack_w(const float* __restrict__ W,
                                              _Float16* __restrict__ Wp) {
    unsigned tid = blockIdx.x * 256 + threadIdx.x;   // 110592 = 1152*96
    unsigned n = tid / 96u;
    unsigned kc = tid - n * 96u;
    f32x8v x = *(const f32x8v*)(W + (size_t)n * IN_DIM + kc * 8u);
    f16x8 h = __builtin_convertvector(x, f16x8);
    unsigned c = (n >> 4) * 1536u + kc * 16u + (n & 15u);
    ((f16x8*)Wp)[c] = h;
}

// ---------------------------------------------------------------------------
// Fused: stage A fp32->f16 into LDS once (full K resident), barrier-free
// MFMA loop with register-direct W fragments, PE-gather epilogue.
// ---------------------------------------------------------------------------
__device__ __forceinline__ void load_frags(const _Float16* sA, const f16x8* pw,
                                           int l15, int quad, int ntc, int ks,
                                           f16x8 af[4], f16x8 bb[3][2]) {
#pragma unroll
    for (int mi = 0; mi < 4; mi++)
        af[mi] = *(const f16x8*)&sA[(mi * 16 + l15) * LDA + ks * 32 + quad * 8];
#pragma unroll
    for (int j = 0; j < 3; j++)
#pragma unroll
        for (int ni = 0; ni < 2; ni++)
            bb[j][ni] = pw[(size_t)(ntc + j) * 12288 + ni * 1536 + ks * 64];
}

__device__ __forceinline__ void do_mfma(const f16x8 af[4], const f16x8 bb[3][2],
                                        f32x4 acc[3][4][2]) {
#pragma unroll
    for (int j = 0; j < 3; j++)
#pragma unroll
        for (int mi = 0; mi < 4; mi++)
#pragma unroll
            for (int ni = 0; ni < 2; ni++)
                acc[j][mi][ni] = __builtin_amdgcn_mfma_f32_16x16x32_f16(
                    af[mi], bb[j][ni], acc[j][mi][ni], 0, 0, 0);
}

__global__ __launch_bounds__(256, 1) void gemm_pe(
    const float* __restrict__ A,        // [M, 768] fp32
    const _Float16* __restrict__ Wp,    // packed f16 fragments
    const int* __restrict__ pos,        // [M,2]
    const int* __restrict__ pad,        // [M]
    const float* __restrict__ table,    // [2,64,1152] fp32
    float* __restrict__ out) {          // [M,1152] fp32
    __shared__ _Float16 sA[BM * LDA];   // 99,328 B; 1 block/CU

    const int m0 = blockIdx.x * BM;
    const int t = threadIdx.x;
    const int lane = t & 63;
    const int w = t >> 6;               // wave 0..3 -> col group w*32
    const int quad = lane >> 4;
    const int l15 = lane & 15;

    // ---- stage A: 64x768 fp32 -> f16 LDS, coalesced 32B/lane ----
    {
        const float* gA = A + (size_t)m0 * IN_DIM;
#pragma unroll 4
        for (int i = 0; i < 24; i++) {
            int c = t + i * 256;                 // 0..6143 (64 rows x 96 chunks)
            int row = c / 96;
            int col8 = c - row * 96;
            f32x8v x = *(const f32x8v*)(gA + (size_t)row * IN_DIM + col8 * 8);
            f16x8 h = __builtin_convertvector(x, f16x8);
            *(f16x8*)&sA[row * LDA + col8 * 8] = h;
        }
    }
    __syncthreads();   // the ONLY barrier in the kernel

    // per-wave W base: n16 = nt*8 + w*2 + ni
    const f16x8* pw = (const f16x8*)Wp + (size_t)(w * 2) * 1536 + lane;

    for (int ntc = 0; ntc < 9; ntc += 3) {   // 3 n-tiles (384 cols) per pass
        f32x4 acc[3][4][2];
#pragma unroll
        for (int j = 0; j < 3; j++)
#pragma unroll
            for (int mi = 0; mi < 4; mi++)
#pragma unroll
                for (int ni = 0; ni < 2; ni++) acc[j][mi][ni] = (f32x4)0.f;

        // 2-stage software pipeline: loads for ks+1 issued before MFMAs of ks
        f16x8 afA[4], afB[4], bA[3][2], bB[3][2];
        load_frags(sA, pw, l15, quad, ntc, 0, afA, bA);
        for (int ks = 0; ks < KSTEPS; ks += 2) {
            load_frags(sA, pw, l15, quad, ntc, ks + 1, afB, bB);
            do_mfma(afA, bA, acc);
            if (ks + 2 < KSTEPS) load_frags(sA, pw, l15, quad, ntc, ks + 2, afA, bA);
            do_mfma(afB, bB, acc);
        }

        // ---- epilogue: C/D layout col=l15, row=quad*4+r (m89-verified) ----
#pragma unroll
        for (int j = 0; j < 3; j++) {
            const int gn0 = (ntc + j) * 128 + w * 32;
#pragma unroll
            for (int mi = 0; mi < 4; mi++) {
#pragma unroll
                for (int r = 0; r < 4; r++) {
                    const int gm = m0 + mi * 16 + quad * 4 + r;
                    int px = pos[gm * 2];
                    int py = pos[gm * 2 + 1];
                    px = px < 0 ? 0 : px;
                    py = py < 0 ? 0 : py;
                    const int isPad = pad[gm];
                    const float* rx = table + (size_t)px * HIDDEN;
                    const float* ry = table + (size_t)(POS_SIZE + py) * HIDDEN;
                    float* orow = out + (size_t)gm * HIDDEN;
#pragma unroll
                    for (int ni = 0; ni < 2; ni++) {
                        const int gn = gn0 + ni * 16 + l15;
                        float pe = isPad ? 0.f : (rx[gn] + ry[gn]);
                        orow[gn] = acc[j][mi][ni][r] + pe;
                    }
                }
            }
        }
    }
}

// ---------------- fp32 fallback (only if ws too small) ----------------
__global__ __launch_bounds__(256) void fallback_naive(const float* __restrict__ A,
                                                      const float* __restrict__ W,
                                                      const int* __restrict__ pos,
                                                      const int* __restrict__ pad,
                                                      const float* __restrict__ table,
                                                      float* __restrict__ out) {
    long idx = (long)blockIdx.x * 256 + threadIdx.x;
    const long total = (long)M_TOTAL * HIDDEN;
    if (idx >= total) return;
    int m = (int)(idx / HIDDEN);
    int n = (int)(idx - (long)m * HIDDEN);
    const float* a = A + (size_t)m * IN_DIM;
    const float* wv = W + (size_t)n * IN_DIM;
    float s = 0.f;
    for (int k = 0; k < IN_DIM; k++) s += a[k] * wv[k];
    int px = pos[m * 2]; if (px < 0) px = 0;
    int py = pos[m * 2 + 1]; if (py < 0) py = 0;
    float pe = pad[m] ? 0.f : (table[(size_t)px * HIDDEN + n] +
                               table[(size_t)(POS_SIZE + py) * HIDDEN + n]);
    out[idx] = s + pe;
}

extern "C" void kernel_launch(void* const* d_in, const int* in_sizes, int n_in,
                              void* d_out, int out_size, void* d_ws, size_t ws_size,
                              hipStream_t stream) {
    const float* pixel = (const float*)d_in[0];
    const int* pos = (const int*)d_in[1];
    const int* pad = (const int*)d_in[2];
    const float* W = (const float*)d_in[3];
    const float* table = (const float*)d_in[4];
    float* out = (float*)d_out;

    const size_t nW = (size_t)HIDDEN * IN_DIM;   // 884,736 halves = 1.77 MB
    if (ws_size >= nW * sizeof(_Float16)) {
        _Float16* Wp = (_Float16*)d_ws;
        pack_w<<<432, 256, 0, stream>>>(W, Wp);
        gemm_pe<<<M_TOTAL / BM, 256, 0, stream>>>(pixel, Wp, pos, pad, table, out);
    } else {
        long total = (long)M_TOTAL * HIDDEN;
        fallback_naive<<<(int)((total + 255) / 256), 256, 0, stream>>>(pixel, W, pos, pad,
                                                                       table, out);
    }
}

// Round 3
// 960.208 us; speedup vs baseline: 1.1707x; 1.1707x over previous
//
#include <hip/hip_runtime.h>

#define HIDDEN 1152
#define IN_DIM 768
#define POS_SIZE 64
#define M_TOTAL (16 * 4096)

#define BM 64
#define KSTEPS 24          /* 768 / 32 */
#define LDA 776            /* LDS row stride in halves: 768 + 8 -> 1552 B rows, 2-way banks only */

typedef _Float16 f16x8 __attribute__((ext_vector_type(8)));
typedef float f32x4 __attribute__((ext_vector_type(4)));
typedef float f32x8v __attribute__((ext_vector_type(8)));

// ---------------------------------------------------------------------------
// Pack W fp32 [1152][768] row-major -> f16, fragment-ordered (verified r2):
//   chunk(n16, ks, lane) at index n16*1536 + ks*64 + lane
//   holds Wh[n16*16 + (lane&15)][ks*32 + (lane>>4)*8 .. +8)
// ---------------------------------------------------------------------------
__global__ __launch_bounds__(256) void pack_w(const float* __restrict__ W,
                                              _Float16* __restrict__ Wp) {
    unsigned tid = blockIdx.x * 256 + threadIdx.x;   // 110592 = 1152*96
    unsigned n = tid / 96u;
    unsigned kc = tid - n * 96u;
    f32x8v x = *(const f32x8v*)(W + (size_t)n * IN_DIM + kc * 8u);
    f16x8 h = __builtin_convertvector(x, f16x8);
    unsigned c = (n >> 4) * 1536u + kc * 16u + (n & 15u);
    ((f16x8*)Wp)[c] = h;
}

// ---------------------------------------------------------------------------
// Fused: stage A fp32->f16 into LDS once (full K resident), barrier-free
// MFMA loop with register-direct W fragments, PE-gather epilogue.
// 512 threads = 8 waves (2 m-rows x 4 n-cols) -> 2 waves/SIMD at 1 block/CU.
// ---------------------------------------------------------------------------
__device__ __forceinline__ void load_frags(const _Float16* sA, const f16x8* pwb,
                                           int arow0, int quad, int npass, int ks,
                                           f16x8 af[2], f16x8 bb[6]) {
#pragma unroll
    for (int mi = 0; mi < 2; mi++)
        af[mi] = *(const f16x8*)&sA[(arow0 + mi * 16) * LDA + ks * 32 + quad * 8];
#pragma unroll
    for (int ni = 0; ni < 6; ni++)
        bb[ni] = pwb[npass * 36864 + ni * 1536 + ks * 64];
}

__device__ __forceinline__ void do_mfma(const f16x8 af[2], const f16x8 bb[6],
                                        f32x4 acc[2][6]) {
#pragma unroll
    for (int mi = 0; mi < 2; mi++)
#pragma unroll
        for (int ni = 0; ni < 6; ni++)
            acc[mi][ni] = __builtin_amdgcn_mfma_f32_16x16x32_f16(af[mi], bb[ni],
                                                                 acc[mi][ni], 0, 0, 0);
}

__global__ __launch_bounds__(512, 2) void gemm_pe(
    const float* __restrict__ A,        // [M, 768] fp32
    const _Float16* __restrict__ Wp,    // packed f16 fragments
    const int* __restrict__ pos,        // [M,2]
    const int* __restrict__ pad,        // [M]
    const float* __restrict__ table,    // [2,64,1152] fp32
    float* __restrict__ out) {          // [M,1152] fp32
    __shared__ _Float16 sA[BM * LDA];   // 99,328 B; 1 block/CU

    const int m0 = blockIdx.x * BM;
    const int t = threadIdx.x;
    const int lane = t & 63;
    const int w = t >> 6;               // 8 waves: (w>>2) = m-half, (w&3) = n-quarter
    const int quad = lane >> 4;
    const int l15 = lane & 15;
    const int arow0 = (w >> 2) * 32 + l15;   // A frag row base (+ mi*16)
    const int wn = (w & 3) * 96;             // wave col base within 384-col pass

    // ---- stage A: 64x768 fp32 -> f16 LDS, coalesced 32B/lane ----
    {
        const float* gA = A + (size_t)m0 * IN_DIM;
#pragma unroll 4
        for (int i = 0; i < 12; i++) {
            int c = t + i * 512;                 // 0..6143 (64 rows x 96 chunks)
            int row = c / 96;
            int col8 = c - row * 96;
            f32x8v x = *(const f32x8v*)(gA + (size_t)row * IN_DIM + col8 * 8);
            f16x8 h = __builtin_convertvector(x, f16x8);
            *(f16x8*)&sA[row * LDA + col8 * 8] = h;
        }
    }
    __syncthreads();   // the ONLY barrier in the kernel

    // per-wave packed-W base: n16 = npass*24 + (w&3)*6 + ni
    const f16x8* pwb = (const f16x8*)Wp + (size_t)((w & 3) * 6) * 1536 + lane;

    for (int npass = 0; npass < 3; npass++) {   // 384 cols per pass
        f32x4 acc[2][6];
#pragma unroll
        for (int mi = 0; mi < 2; mi++)
#pragma unroll
            for (int ni = 0; ni < 6; ni++) acc[mi][ni] = (f32x4)0.f;

        // 2-stage software pipeline: loads for ks+1 issued before MFMAs of ks
        f16x8 afA[2], afB[2], bA[6], bB[6];
        load_frags(sA, pwb, arow0, quad, npass, 0, afA, bA);
        for (int ks = 0; ks < KSTEPS; ks += 2) {
            load_frags(sA, pwb, arow0, quad, npass, ks + 1, afB, bB);
            do_mfma(afA, bA, acc);
            if (ks + 2 < KSTEPS) load_frags(sA, pwb, arow0, quad, npass, ks + 2, afA, bA);
            do_mfma(afB, bB, acc);
        }

        // ---- epilogue: C/D layout col=l15, row=quad*4+r (verified r0/r2) ----
        const int gn0 = npass * 384 + wn;
#pragma unroll
        for (int mi = 0; mi < 2; mi++) {
#pragma unroll
            for (int r = 0; r < 4; r++) {
                const int gm = m0 + (w >> 2) * 32 + mi * 16 + quad * 4 + r;
                int px = pos[gm * 2];
                int py = pos[gm * 2 + 1];
                px = px < 0 ? 0 : px;
                py = py < 0 ? 0 : py;
                const int isPad = pad[gm];
                const float* rx = table + (size_t)px * HIDDEN;
                const float* ry = table + (size_t)(POS_SIZE + py) * HIDDEN;
                float* orow = out + (size_t)gm * HIDDEN;
#pragma unroll
                for (int ni = 0; ni < 6; ni++) {
                    const int gn = gn0 + ni * 16 + l15;
                    float pe = isPad ? 0.f : (rx[gn] + ry[gn]);
                    orow[gn] = acc[mi][ni][r] + pe;
                }
            }
        }
    }
}

// ---------------- fp32 fallback (only if ws too small) ----------------
__global__ __launch_bounds__(256) void fallback_naive(const float* __restrict__ A,
                                                      const float* __restrict__ W,
                                                      const int* __restrict__ pos,
                                                      const int* __restrict__ pad,
                                                      const float* __restrict__ table,
                                                      float* __restrict__ out) {
    long idx = (long)blockIdx.x * 256 + threadIdx.x;
    const long total = (long)M_TOTAL * HIDDEN;
    if (idx >= total) return;
    int m = (int)(idx / HIDDEN);
    int n = (int)(idx - (long)m * HIDDEN);
    const float* a = A + (size_t)m * IN_DIM;
    const float* wv = W + (size_t)n * IN_DIM;
    float s = 0.f;
    for (int k = 0; k < IN_DIM; k++) s += a[k] * wv[k];
    int px = pos[m * 2]; if (px < 0) px = 0;
    int py = pos[m * 2 + 1]; if (py < 0) py = 0;
    float pe = pad[m] ? 0.f : (table[(size_t)px * HIDDEN + n] +
                               table[(size_t)(POS_SIZE + py) * HIDDEN + n]);
    out[idx] = s + pe;
}

extern "C" void kernel_launch(void* const* d_in, const int* in_sizes, int n_in,
                              void* d_out, int out_size, void* d_ws, size_t ws_size,
                              hipStream_t stream) {
    const float* pixel = (const float*)d_in[0];
    const int* pos = (const int*)d_in[1];
    const int* pad = (const int*)d_in[2];
    const float* W = (const float*)d_in[3];
    const float* table = (const float*)d_in[4];
    float* out = (float*)d_out;

    const size_t nW = (size_t)HIDDEN * IN_DIM;   // 884,736 halves = 1.77 MB
    if (ws_size >= nW * sizeof(_Float16)) {
        _Float16* Wp = (_Float16*)d_ws;
        pack_w<<<432, 256, 0, stream>>>(W, Wp);
        gemm_pe<<<M_TOTAL / BM, 512, 0, stream>>>(pixel, Wp, pos, pad, table, out);
    } else {
        long total = (long)M_TOTAL * HIDDEN;
        fallback_naive<<<(int)((total + 255) / 256), 256, 0, stream>>>(pixel, W, pos, pad,
                                                                       table, out);
    }
}

// Round 4
// 648.726 us; speedup vs baseline: 1.7328x; 1.4801x over previous
//
#include <hip/hip_runtime.h>

#define HIDDEN 1152
#define IN_DIM 768
#define POS_SIZE 64
#define M_TOTAL (16 * 4096)

#define BM 64
#define LDA 776            /* LDS A row stride in halves (768 + 8) */
#define NPASS 6            /* n-passes of 192 cols */
#define NSTAGE 12          /* stages per pass, each stage = K-depth 64 (2 MFMA k-steps) */
#define TOTSTAGE (NPASS * NSTAGE)

typedef _Float16 f16x8 __attribute__((ext_vector_type(8)));
typedef float f32x4 __attribute__((ext_vector_type(4)));
typedef float f32x8v __attribute__((ext_vector_type(8)));

typedef __attribute__((address_space(1))) const void global_cv;
typedef __attribute__((address_space(3))) void lds_v;

__device__ __forceinline__ void async16(const void* g, void* l) {
    __builtin_amdgcn_global_load_lds((global_cv*)g, (lds_v*)l, 16, 0, 0);
}

// ---------------------------------------------------------------------------
// Pack W fp32 [1152][768] row-major -> f16, fragment-ordered (refcheck'd r2/r3):
//   chunk(n16, ks, lane) at 16B-chunk index n16*1536 + ks*64 + lane
//   holds Wh[n16*16 + (lane&15)][ks*32 + (lane>>4)*8 .. +8)
// ---------------------------------------------------------------------------
__global__ __launch_bounds__(256) void pack_w(const float* __restrict__ W,
                                              _Float16* __restrict__ Wp) {
    unsigned tid = blockIdx.x * 256 + threadIdx.x;   // 110592 = 1152*96
    unsigned n = tid / 96u;
    unsigned kc = tid - n * 96u;
    f32x8v x = *(const f32x8v*)(W + (size_t)n * IN_DIM + kc * 8u);
    f16x8 h = __builtin_convertvector(x, f16x8);
    unsigned c = (n >> 4) * 1536u + kc * 16u + (n & 15u);
    ((f16x8*)Wp)[c] = h;
}

// ---------------------------------------------------------------------------
// Stage one B tile (192 cols x K=64) into LDS: 1536 chunks of 16B = 24 KB.
// LDS layout: chunk c = kk*768 + n16l*64 + lane  (kk = k-substep 0..1,
// n16l = 0..11 col-16-group within pass, lane = frag lane).
// Wave-uniform LDS dest (base + lane*16) as required by global_load_lds.
// ---------------------------------------------------------------------------
__device__ __forceinline__ void stageB(const f16x8* wp, _Float16* dstBuf,
                                       int t, int pass, int s) {
#pragma unroll
    for (int i = 0; i < 3; i++) {
        int c = t + i * 512;            // 0..1535
        int kk = c / 768;               // uniform within a wave (64 | 768)
        int rem = c - kk * 768;
        int n16l = rem >> 6;
        int lc = rem & 63;
        size_t srcIdx = (size_t)(pass * 12 + n16l) * 1536 +
                        (size_t)(2 * s + kk) * 64 + lc;
        async16(wp + srcIdx, dstBuf + (size_t)c * 8);
    }
}

// ---------------------------------------------------------------------------
// Fused GEMM+PE: A (fp32) -> f16 LDS once (full K resident); B double-buffered
// in LDS via global_load_lds with counted vmcnt (T3+T4); PE-gather epilogue.
// 8 waves = 2m x 4n; per wave per stage: 2m x 3n x 2k = 12 MFMA.
// ---------------------------------------------------------------------------
__global__ __launch_bounds__(512, 2) void gemm_pe(
    const float* __restrict__ A,        // [M, 768] fp32
    const _Float16* __restrict__ Wp,    // packed f16 fragments
    const int* __restrict__ pos,        // [M,2]
    const int* __restrict__ pad,        // [M]
    const float* __restrict__ table,    // [2,64,1152] fp32
    float* __restrict__ out) {          // [M,1152] fp32
    __shared__ __align__(16) _Float16 sA[BM * LDA];   // 99,328 B
    __shared__ __align__(16) _Float16 sB[2][12288];   // 2 x 24,576 B; total 148,480 B

    const int m0 = blockIdx.x * BM;
    const int t = threadIdx.x;
    const int lane = t & 63;
    const int w = t >> 6;
    const int quad = lane >> 4;
    const int l15 = lane & 15;
    const int mw = w >> 2;              // m-half (0..1)
    const int nw = w & 3;               // n-quarter (0..3)
    const int arow0 = mw * 32 + l15;

    const f16x8* wp = (const f16x8*)Wp;

    // kick off B stage 0 immediately (overlaps A staging)
    stageB(wp, sB[0], t, 0, 0);

    // hoist per-thread PE metadata (8 output rows/thread, reused all 6 passes)
    int pxv[8], pyv[8], pdv[8];
#pragma unroll
    for (int mi = 0; mi < 2; mi++)
#pragma unroll
        for (int r = 0; r < 4; r++) {
            const int gm = m0 + mw * 32 + mi * 16 + quad * 4 + r;
            int px = pos[gm * 2];
            int py = pos[gm * 2 + 1];
            pxv[mi * 4 + r] = px < 0 ? 0 : px;
            pyv[mi * 4 + r] = py < 0 ? 0 : py;
            pdv[mi * 4 + r] = pad[gm];
        }

    // stage A: 64 x 768 fp32 -> f16 LDS, 32B/lane coalesced
    {
        const float* gA = A + (size_t)m0 * IN_DIM;
#pragma unroll 4
        for (int i = 0; i < 12; i++) {
            int c = t + i * 512;                 // 0..6143 (64 rows x 96 chunks)
            int row = c / 96;
            int col8 = c - row * 96;
            f32x8v x = *(const f32x8v*)(gA + (size_t)row * IN_DIM + col8 * 8);
            f16x8 h = __builtin_convertvector(x, f16x8);
            *(f16x8*)&sA[row * LDA + col8 * 8] = h;
        }
    }
    __syncthreads();   // full drain: A resident; stageB(0) also complete

    for (int pass = 0; pass < NPASS; pass++) {
        f32x4 acc[2][3];
#pragma unroll
        for (int mi = 0; mi < 2; mi++)
#pragma unroll
            for (int ni = 0; ni < 3; ni++) acc[mi][ni] = (f32x4)0.f;

        for (int s = 0; s < NSTAGE; s++) {
            const int g = pass * NSTAGE + s;
            // issue next stage, then counted wait: stage g complete, g+1 in flight
            if (g < TOTSTAGE - 1) {
                const int gn = g + 1;
                const int pn = gn / NSTAGE;
                const int sn = gn - pn * NSTAGE;
                stageB(wp, sB[gn & 1], t, pn, sn);
                asm volatile("s_waitcnt vmcnt(3)" ::: "memory");
            } else {
                asm volatile("s_waitcnt vmcnt(0)" ::: "memory");
            }
            asm volatile("s_barrier" ::: "memory");   // all waves: stage g visible

            const _Float16* bbuf = sB[g & 1];
            f16x8 af[2][2], bf[3][2];
#pragma unroll
            for (int mi = 0; mi < 2; mi++)
#pragma unroll
                for (int kk = 0; kk < 2; kk++)
                    af[mi][kk] = *(const f16x8*)&sA[(arow0 + mi * 16) * LDA +
                                                    (2 * s + kk) * 32 + quad * 8];
#pragma unroll
            for (int ni = 0; ni < 3; ni++)
#pragma unroll
                for (int kk = 0; kk < 2; kk++)
                    bf[ni][kk] = *(const f16x8*)&bbuf[((kk * 12 + nw * 3 + ni) * 64 +
                                                       lane) * 8];
#pragma unroll
            for (int kk = 0; kk < 2; kk++)
#pragma unroll
                for (int mi = 0; mi < 2; mi++)
#pragma unroll
                    for (int ni = 0; ni < 3; ni++)
                        acc[mi][ni] = __builtin_amdgcn_mfma_f32_16x16x32_f16(
                            af[mi][kk], bf[ni][kk], acc[mi][ni], 0, 0, 0);
            asm volatile("s_barrier" ::: "memory");   // reads done: buf may be reused
        }

        // epilogue: C/D layout col=l15, row=quad*4+r (refcheck'd r0/r2/r3)
        const int gn0 = pass * 192 + nw * 48;
#pragma unroll
        for (int mi = 0; mi < 2; mi++) {
#pragma unroll
            for (int r = 0; r < 4; r++) {
                const int gm = m0 + mw * 32 + mi * 16 + quad * 4 + r;
                const int idx = mi * 4 + r;
                const float* rx = table + (size_t)pxv[idx] * HIDDEN;
                const float* ry = table + (size_t)(POS_SIZE + pyv[idx]) * HIDDEN;
                float* orow = out + (size_t)gm * HIDDEN;
                const int isPad = pdv[idx];
#pragma unroll
                for (int ni = 0; ni < 3; ni++) {
                    const int gn = gn0 + ni * 16 + l15;
                    float pe = isPad ? 0.f : (rx[gn] + ry[gn]);
                    orow[gn] = acc[mi][ni][r] + pe;
                }
            }
        }
    }
}

// ---------------- fp32 fallback (only if ws too small) ----------------
__global__ __launch_bounds__(256) void fallback_naive(const float* __restrict__ A,
                                                      const float* __restrict__ W,
                                                      const int* __restrict__ pos,
                                                      const int* __restrict__ pad,
                                                      const float* __restrict__ table,
                                                      float* __restrict__ out) {
    long idx = (long)blockIdx.x * 256 + threadIdx.x;
    const long total = (long)M_TOTAL * HIDDEN;
    if (idx >= total) return;
    int m = (int)(idx / HIDDEN);
    int n = (int)(idx - (long)m * HIDDEN);
    const float* a = A + (size_t)m * IN_DIM;
    const float* wv = W + (size_t)n * IN_DIM;
    float s = 0.f;
    for (int k = 0; k < IN_DIM; k++) s += a[k] * wv[k];
    int px = pos[m * 2]; if (px < 0) px = 0;
    int py = pos[m * 2 + 1]; if (py < 0) py = 0;
    float pe = pad[m] ? 0.f : (table[(size_t)px * HIDDEN + n] +
                               table[(size_t)(POS_SIZE + py) * HIDDEN + n]);
    out[idx] = s + pe;
}

extern "C" void kernel_launch(void* const* d_in, const int* in_sizes, int n_in,
                              void* d_out, int out_size, void* d_ws, size_t ws_size,
                              hipStream_t stream) {
    const float* pixel = (const float*)d_in[0];
    const int* pos = (const int*)d_in[1];
    const int* pad = (const int*)d_in[2];
    const float* W = (const float*)d_in[3];
    const float* table = (const float*)d_in[4];
    float* out = (float*)d_out;

    const size_t nW = (size_t)HIDDEN * IN_DIM;   // 884,736 halves = 1.77 MB
    if (ws_size >= nW * sizeof(_Float16)) {
        _Float16* Wp = (_Float16*)d_ws;
        pack_w<<<432, 256, 0, stream>>>(W, Wp);
        gemm_pe<<<M_TOTAL / BM, 512, 0, stream>>>(pixel, Wp, pos, pad, table, out);
    } else {
        long total = (long)M_TOTAL * HIDDEN;
        fallback_naive<<<(int)((total + 255) / 256), 256, 0, stream>>>(pixel, W, pos, pad,
                                                                       table, out);
    }
}

// Round 5
// 616.407 us; speedup vs baseline: 1.8236x; 1.0524x over previous
//
#include <hip/hip_runtime.h>

#define HIDDEN 1152
#define IN_DIM 768
#define POS_SIZE 64
#define M_TOTAL (16 * 4096)

#define BM 64
#define NPASS 9            /* passes of 128 cols */
#define NSTAGE 12          /* K-stages per pass, K-depth 64 each */
#define TOTSTAGE (NPASS * NSTAGE)   /* 108 */

typedef _Float16 f16x8 __attribute__((ext_vector_type(8)));
typedef float f32x4 __attribute__((ext_vector_type(4)));
typedef float f32x8v __attribute__((ext_vector_type(8)));

typedef __attribute__((address_space(1))) const void global_cv;
typedef __attribute__((address_space(3))) void lds_v;

__device__ __forceinline__ void async16(const void* g, void* l) {
    __builtin_amdgcn_global_load_lds((global_cv*)g, (lds_v*)l, 16, 0, 0);
}

// ---------------------------------------------------------------------------
// Pack W fp32 [1152][768] row-major -> f16, fragment-ordered (refcheck'd r2-r4):
//   chunk(n16, ks, lane) at 16B-chunk index n16*1536 + ks*64 + lane
//   holds Wh[n16*16 + (lane&15)][ks*32 + (lane>>4)*8 .. +8)
// ---------------------------------------------------------------------------
__global__ __launch_bounds__(256) void pack_w(const float* __restrict__ W,
                                              _Float16* __restrict__ Wp) {
    unsigned tid = blockIdx.x * 256 + threadIdx.x;   // 110592 = 1152*96
    unsigned n = tid / 96u;
    unsigned kc = tid - n * 96u;
    f32x8v x = *(const f32x8v*)(W + (size_t)n * IN_DIM + kc * 8u);
    f16x8 h = __builtin_convertvector(x, f16x8);
    unsigned c = (n >> 4) * 1536u + kc * 16u + (n & 15u);
    ((f16x8*)Wp)[c] = h;
}

// ---------------------------------------------------------------------------
// Stage one B tile (128 cols x K=64) = 1024 chunks of 16B = 16 KB.
// LDS chunk c = kk*512 + n16l*64 + lane (kk = 32-k-substep, n16l = col-16 group).
// 2 chunks/thread; wave-uniform LDS dest (c/64 uniform per wave).
// ---------------------------------------------------------------------------
__device__ __forceinline__ void stageB(const f16x8* wp, _Float16* dstBuf,
                                       int t, int g) {
    int p = g / NSTAGE;
    int s = g - p * NSTAGE;
#pragma unroll
    for (int i = 0; i < 2; i++) {
        int c = t + i * 512;            // 0..1023
        int kk = c >> 9;
        int n16l = (c >> 6) & 7;
        int lc = c & 63;
        size_t srcIdx = (size_t)(p * 8 + n16l) * 1536 + (size_t)(2 * s + kk) * 64 + lc;
        async16(wp + srcIdx, dstBuf + (size_t)c * 8);
    }
}

// ---------------------------------------------------------------------------
// Fused GEMM+PE. A (fp32) -> f16 LDS once, K-major XOR-swizzled (conflict-free
// frag reads). B: 3-deep LDS ring via global_load_lds, counted vmcnt(4)
// (2 stages in flight, never drained to 0 in steady state). 8 waves = 2m x 4n.
// Per wave per stage: 2mi x 2ni x 2kk = 8 MFMA.
// ---------------------------------------------------------------------------
__global__ __launch_bounds__(512, 2) void gemm_pe(
    const float* __restrict__ A,        // [M, 768] fp32
    const _Float16* __restrict__ Wp,    // packed f16 fragments
    const int* __restrict__ pos,        // [M,2]
    const int* __restrict__ pad,        // [M]
    const float* __restrict__ table,    // [2,64,1152] fp32
    float* __restrict__ out) {          // [M,1152] fp32
    __shared__ __align__(16) _Float16 sA[6144 * 8];   // 98,304 B (K-major chunks)
    __shared__ __align__(16) _Float16 sB[3][8192];    // 3 x 16,384 B; total 147,456 B

    const int m0 = blockIdx.x * BM;
    const int t = threadIdx.x;
    const int lane = t & 63;
    const int w = t >> 6;
    const int quad = lane >> 4;
    const int l15 = lane & 15;
    const int mw = w >> 2;              // m-half (0..1)
    const int nw = w & 3;               // n-quarter (0..3)

    const f16x8* wp = (const f16x8*)Wp;

    // prologue: stages 0 and 1 in flight immediately (overlap with A staging)
    stageB(wp, sB[0], t, 0);
    stageB(wp, sB[1], t, 1);

    // hoist per-thread PE metadata (8 output rows/thread, reused all passes)
    int pxv[8], pyv[8], pdv[8];
#pragma unroll
    for (int mi = 0; mi < 2; mi++)
#pragma unroll
        for (int r = 0; r < 4; r++) {
            const int gm = m0 + mw * 32 + mi * 16 + quad * 4 + r;
            int px = pos[gm * 2];
            int py = pos[gm * 2 + 1];
            pxv[mi * 4 + r] = px < 0 ? 0 : px;
            pyv[mi * 4 + r] = py < 0 ? 0 : py;
            pdv[mi * 4 + r] = pad[gm];
        }

    // stage A: 64 x 768 fp32 -> f16, K-major chunk layout with XOR swizzle:
    // chunk(kc,row) = kc*64 + (row ^ ((kc&7)<<1)); holds A[m0+row][kc*8..+8)
    {
        const float* gA = A + (size_t)m0 * IN_DIM;
#pragma unroll 4
        for (int i = 0; i < 12; i++) {
            int c = t + i * 512;                 // 0..6143 (64 rows x 96 k-chunks)
            int row = c / 96;
            int kc = c - row * 96;
            f32x8v x = *(const f32x8v*)(gA + (size_t)row * IN_DIM + kc * 8);
            f16x8 h = __builtin_convertvector(x, f16x8);
            int chunk = kc * 64 + (row ^ ((kc & 7) << 1));
            *(f16x8*)&sA[(size_t)chunk * 8] = h;
        }
    }
    __syncthreads();   // A resident; S0/S1 DMA drained (prologue only)

    const int arow_base = mw * 32 + l15;

    for (int pass = 0; pass < NPASS; pass++) {
        f32x4 acc[2][2];
#pragma unroll
        for (int mi = 0; mi < 2; mi++)
#pragma unroll
            for (int ni = 0; ni < 2; ni++) acc[mi][ni] = (f32x4)0.f;

        for (int s = 0; s < NSTAGE; s++) {
            const int g = pass * NSTAGE + s;
            // issue stage g+2 into buf[(g+2)%3] (== buf reused from stage g-1,
            // whose reads completed before the end-barrier of g-1)
            if (g < TOTSTAGE - 2) {
                const int g2 = g + 2;
                stageB(wp, sB[g2 - (g2 / 3) * 3], t, g2);
                asm volatile("s_waitcnt vmcnt(4)" ::: "memory");  // g done; g+1,g+2 in flight
            } else if (g == TOTSTAGE - 2) {
                asm volatile("s_waitcnt vmcnt(2)" ::: "memory");
            } else {
                asm volatile("s_waitcnt vmcnt(0)" ::: "memory");
            }
            asm volatile("s_barrier" ::: "memory");   // stage g visible to all waves

            const _Float16* bbuf = sB[g - (g / 3) * 3];
            f16x8 af[2][2], bf[2][2];
#pragma unroll
            for (int mi = 0; mi < 2; mi++)
#pragma unroll
                for (int kk = 0; kk < 2; kk++) {
                    const int kc = (2 * s + kk) * 4 + quad;
                    const int row = (arow_base + mi * 16) ^ ((kc & 7) << 1);
                    af[mi][kk] = *(const f16x8*)&sA[(size_t)(kc * 64 + row) * 8];
                }
#pragma unroll
            for (int ni = 0; ni < 2; ni++)
#pragma unroll
                for (int kk = 0; kk < 2; kk++)
                    bf[ni][kk] = *(const f16x8*)&bbuf[(size_t)((kk * 8 + nw * 2 + ni) * 64 +
                                                               lane) * 8];

            __builtin_amdgcn_s_setprio(1);
#pragma unroll
            for (int kk = 0; kk < 2; kk++)
#pragma unroll
                for (int mi = 0; mi < 2; mi++)
#pragma unroll
                    for (int ni = 0; ni < 2; ni++)
                        acc[mi][ni] = __builtin_amdgcn_mfma_f32_16x16x32_f16(
                            af[mi][kk], bf[ni][kk], acc[mi][ni], 0, 0, 0);
            __builtin_amdgcn_s_setprio(0);
            asm volatile("s_barrier" ::: "memory");   // reads of buf done -> reusable
        }

        // epilogue: C/D layout col=l15, row=quad*4+r (refcheck'd r0/r2/r3/r4)
        const int gn0 = pass * 128 + nw * 32;
#pragma unroll
        for (int mi = 0; mi < 2; mi++) {
#pragma unroll
            for (int r = 0; r < 4; r++) {
                const int gm = m0 + mw * 32 + mi * 16 + quad * 4 + r;
                const int idx = mi * 4 + r;
                const float* rx = table + (size_t)pxv[idx] * HIDDEN;
                const float* ry = table + (size_t)(POS_SIZE + pyv[idx]) * HIDDEN;
                float* orow = out + (size_t)gm * HIDDEN;
                const int isPad = pdv[idx];
#pragma unroll
                for (int ni = 0; ni < 2; ni++) {
                    const int gn = gn0 + ni * 16 + l15;
                    float pe = isPad ? 0.f : (rx[gn] + ry[gn]);
                    orow[gn] = acc[mi][ni][r] + pe;
                }
            }
        }
    }
}

// ---------------- fp32 fallback (only if ws too small) ----------------
__global__ __launch_bounds__(256) void fallback_naive(const float* __restrict__ A,
                                                      const float* __restrict__ W,
                                                      const int* __restrict__ pos,
                                                      const int* __restrict__ pad,
                                                      const float* __restrict__ table,
                                                      float* __restrict__ out) {
    long idx = (long)blockIdx.x * 256 + threadIdx.x;
    const long total = (long)M_TOTAL * HIDDEN;
    if (idx >= total) return;
    int m = (int)(idx / HIDDEN);
    int n = (int)(idx - (long)m * HIDDEN);
    const float* a = A + (size_t)m * IN_DIM;
    const float* wv = W + (size_t)n * IN_DIM;
    float s = 0.f;
    for (int k = 0; k < IN_DIM; k++) s += a[k] * wv[k];
    int px = pos[m * 2]; if (px < 0) px = 0;
    int py = pos[m * 2 + 1]; if (py < 0) py = 0;
    float pe = pad[m] ? 0.f : (table[(size_t)px * HIDDEN + n] +
                               table[(size_t)(POS_SIZE + py) * HIDDEN + n]);
    out[idx] = s + pe;
}

extern "C" void kernel_launch(void* const* d_in, const int* in_sizes, int n_in,
                              void* d_out, int out_size, void* d_ws, size_t ws_size,
                              hipStream_t stream) {
    const float* pixel = (const float*)d_in[0];
    const int* pos = (const int*)d_in[1];
    const int* pad = (const int*)d_in[2];
    const float* W = (const float*)d_in[3];
    const float* table = (const float*)d_in[4];
    float* out = (float*)d_out;

    const size_t nW = (size_t)HIDDEN * IN_DIM;   // 884,736 halves = 1.77 MB
    if (ws_size >= nW * sizeof(_Float16)) {
        _Float16* Wp = (_Float16*)d_ws;
        pack_w<<<432, 256, 0, stream>>>(W, Wp);
        gemm_pe<<<M_TOTAL / BM, 512, 0, stream>>>(pixel, Wp, pos, pad, table, out);
    } else {
        long total = (long)M_TOTAL * HIDDEN;
        fallback_naive<<<(int)((total + 255) / 256), 256, 0, stream>>>(pixel, W, pos, pad,
                                                                       table, out);
    }
}

// Round 6
// 597.562 us; speedup vs baseline: 1.8812x; 1.0315x over previous
//
#include <hip/hip_runtime.h>

#define HIDDEN 1152
#define IN_DIM 768
#define POS_SIZE 64
#define M_TOTAL (16 * 4096)

#define BM 64
#define NPASS 9            /* passes of 128 cols; each wave owns 16 cols per pass */
#define NSTAGE 12          /* K-stages per pass, K-depth 64 each */
#define TOTSTAGE (NPASS * NSTAGE)   /* 108 */

typedef _Float16 f16x8 __attribute__((ext_vector_type(8)));
typedef float f32x4 __attribute__((ext_vector_type(4)));
typedef float f32x8v __attribute__((ext_vector_type(8)));

typedef __attribute__((address_space(1))) const void global_cv;
typedef __attribute__((address_space(3))) void lds_v;

__device__ __forceinline__ void async16(const void* g, void* l) {
    __builtin_amdgcn_global_load_lds((global_cv*)g, (lds_v*)l, 16, 0, 0);
}

// ---------------------------------------------------------------------------
// Pack W fp32 [1152][768] row-major -> f16, fragment-ordered (refcheck'd r2-r5):
//   chunk(n16, ks, lane) at 16B-chunk index n16*1536 + ks*64 + lane
//   holds Wh[n16*16 + (lane&15)][ks*32 + (lane>>4)*8 .. +8)
// ---------------------------------------------------------------------------
__global__ __launch_bounds__(256) void pack_w(const float* __restrict__ W,
                                              _Float16* __restrict__ Wp) {
    unsigned tid = blockIdx.x * 256 + threadIdx.x;   // 110592 = 1152*96
    unsigned n = tid / 96u;
    unsigned kc = tid - n * 96u;
    f32x8v x = *(const f32x8v*)(W + (size_t)n * IN_DIM + kc * 8u);
    f16x8 h = __builtin_convertvector(x, f16x8);
    unsigned c = (n >> 4) * 1536u + kc * 16u + (n & 15u);
    ((f16x8*)Wp)[c] = h;
}

// ---------------------------------------------------------------------------
// Fused GEMM+PE, BARRIER-FREE main loop.
// A (fp32) -> f16 LDS once, K-major XOR-swizzled (conflict-free, refcheck'd r5).
// B: per-wave PRIVATE 3-slot LDS ring; each wave DMAs only the 16-col W slice
// it consumes (global_load_lds, counted per-wave vmcnt(4), 2-stage lookahead).
// No cross-wave B dependency => no s_barrier after the A-stage syncthreads.
// 8 waves; per wave per stage: af[4 mi][2 kk] x bf[2 kk] -> 8 MFMA, acc[4].
// ---------------------------------------------------------------------------
__global__ __launch_bounds__(512, 2) void gemm_pe(
    const float* __restrict__ A,        // [M, 768] fp32
    const _Float16* __restrict__ Wp,    // packed f16 fragments
    const int* __restrict__ pos,        // [M,2]
    const int* __restrict__ pad,        // [M]
    const float* __restrict__ table,    // [2,64,1152] fp32
    float* __restrict__ out) {          // [M,1152] fp32
    __shared__ __align__(16) _Float16 sA[6144 * 8];       // 98,304 B (K-major chunks)
    __shared__ __align__(16) _Float16 sB[8 * 3 * 1024];   // 49,152 B; total 147,456 B

    const int m0 = blockIdx.x * BM;
    const int t = threadIdx.x;
    const int lane = t & 63;
    const int w = t >> 6;               // wave 0..7: owns col-16 group w of each pass
    const int quad = lane >> 4;
    const int l15 = lane & 15;

    const f16x8* wp = (const f16x8*)Wp;
    _Float16* myB = &sB[w * 3072];      // private ring: 3 slots x 1024 halves

    // prologue: stages 0,1 of pass 0 in flight (slots 0,1)
#pragma unroll
    for (int g = 0; g < 2; ++g)
#pragma unroll
        for (int kk = 0; kk < 2; ++kk)
            async16(wp + (size_t)(w * 1536 + (2 * g + kk) * 64 + lane),
                    myB + (g * 1024 + kk * 512));

    // hoist per-thread PE metadata: 16 output rows/thread, packed px|py<<8|pad<<16
    int meta[16];
#pragma unroll
    for (int mi = 0; mi < 4; mi++)
#pragma unroll
        for (int r = 0; r < 4; r++) {
            const int gm = m0 + mi * 16 + quad * 4 + r;
            int px = pos[gm * 2];
            int py = pos[gm * 2 + 1];
            px = px < 0 ? 0 : px;
            py = py < 0 ? 0 : py;
            meta[mi * 4 + r] = px | (py << 8) | ((pad[gm] ? 1 : 0) << 16);
        }

    // stage A: 64 x 768 fp32 -> f16, K-major chunks with XOR swizzle (r5):
    // chunk(kc,row) = kc*64 + (row ^ ((kc&7)<<1)); holds A[m0+row][kc*8..+8)
    {
        const float* gA = A + (size_t)m0 * IN_DIM;
#pragma unroll 4
        for (int i = 0; i < 12; i++) {
            int c = t + i * 512;                 // 0..6143 (64 rows x 96 k-chunks)
            int row = c / 96;
            int kc = c - row * 96;
            f32x8v x = *(const f32x8v*)(gA + (size_t)row * IN_DIM + kc * 8);
            f16x8 h = __builtin_convertvector(x, f16x8);
            int chunk = kc * 64 + (row ^ ((kc & 7) << 1));
            *(f16x8*)&sA[(size_t)chunk * 8] = h;
        }
    }
    __syncthreads();   // the ONLY barrier: A resident (also drains prologue DMA)

    for (int pass = 0; pass < NPASS; pass++) {
        f32x4 acc[4];
#pragma unroll
        for (int mi = 0; mi < 4; mi++) acc[mi] = (f32x4)0.f;

        for (int s = 0; s < NSTAGE; s++) {
            const int g = pass * NSTAGE + s;
            // issue stage g+2 into ring slot (g+2)%3, then per-wave counted wait:
            // vmcnt(4) leaves DMA(g+1),DMA(g+2) in flight, guarantees DMA(g) done.
            if (g < TOTSTAGE - 2) {
                const int g2 = g + 2;
                const int p2 = g2 / NSTAGE;
                const int s2 = g2 - p2 * NSTAGE;
                const int slot2 = g2 - (g2 / 3) * 3;
#pragma unroll
                for (int kk = 0; kk < 2; ++kk)
                    async16(wp + (size_t)(p2 * 12288 + w * 1536 + (2 * s2 + kk) * 64 + lane),
                            myB + (slot2 * 1024 + kk * 512));
                asm volatile("s_waitcnt vmcnt(4)" ::: "memory");
            } else if (g == TOTSTAGE - 2) {
                asm volatile("s_waitcnt vmcnt(2)" ::: "memory");
            } else {
                asm volatile("s_waitcnt vmcnt(0)" ::: "memory");
            }

            const int slot = g - (g / 3) * 3;
            f16x8 bf[2];
#pragma unroll
            for (int kk = 0; kk < 2; ++kk)
                bf[kk] = *(const f16x8*)&myB[slot * 1024 + kk * 512 + lane * 8];

            f16x8 af[4][2];
#pragma unroll
            for (int mi = 0; mi < 4; mi++)
#pragma unroll
                for (int kk = 0; kk < 2; kk++) {
                    const int kc = (2 * s + kk) * 4 + quad;
                    const int row = (l15 + mi * 16) ^ ((kc & 7) << 1);
                    af[mi][kk] = *(const f16x8*)&sA[(size_t)(kc * 64 + row) * 8];
                }

            __builtin_amdgcn_s_setprio(1);
#pragma unroll
            for (int kk = 0; kk < 2; kk++)
#pragma unroll
                for (int mi = 0; mi < 4; mi++)
                    acc[mi] = __builtin_amdgcn_mfma_f32_16x16x32_f16(af[mi][kk], bf[kk],
                                                                     acc[mi], 0, 0, 0);
            __builtin_amdgcn_s_setprio(0);
        }

        // epilogue: C/D layout col=l15, row=quad*4+r (refcheck'd r0/r2-r5)
        const int gn = pass * 128 + w * 16 + l15;
#pragma unroll
        for (int mi = 0; mi < 4; mi++)
#pragma unroll
            for (int r = 0; r < 4; r++) {
                const int gm = m0 + mi * 16 + quad * 4 + r;
                const int mv = meta[mi * 4 + r];
                const int px = mv & 255;
                const int py = (mv >> 8) & 255;
                const int isPad = mv >> 16;
                float pe = isPad ? 0.f
                                 : (table[(size_t)px * HIDDEN + gn] +
                                    table[(size_t)(POS_SIZE + py) * HIDDEN + gn]);
                out[(size_t)gm * HIDDEN + gn] = acc[mi][r] + pe;
            }
    }
}

// ---------------- fp32 fallback (only if ws too small) ----------------
__global__ __launch_bounds__(256) void fallback_naive(const float* __restrict__ A,
                                                      const float* __restrict__ W,
                                                      const int* __restrict__ pos,
                                                      const int* __restrict__ pad,
                                                      const float* __restrict__ table,
                                                      float* __restrict__ out) {
    long idx = (long)blockIdx.x * 256 + threadIdx.x;
    const long total = (long)M_TOTAL * HIDDEN;
    if (idx >= total) return;
    int m = (int)(idx / HIDDEN);
    int n = (int)(idx - (long)m * HIDDEN);
    const float* a = A + (size_t)m * IN_DIM;
    const float* wv = W + (size_t)n * IN_DIM;
    float s = 0.f;
    for (int k = 0; k < IN_DIM; k++) s += a[k] * wv[k];
    int px = pos[m * 2]; if (px < 0) px = 0;
    int py = pos[m * 2 + 1]; if (py < 0) py = 0;
    float pe = pad[m] ? 0.f : (table[(size_t)px * HIDDEN + n] +
                               table[(size_t)(POS_SIZE + py) * HIDDEN + n]);
    out[idx] = s + pe;
}

extern "C" void kernel_launch(void* const* d_in, const int* in_sizes, int n_in,
                              void* d_out, int out_size, void* d_ws, size_t ws_size,
                              hipStream_t stream) {
    const float* pixel = (const float*)d_in[0];
    const int* pos = (const int*)d_in[1];
    const int* pad = (const int*)d_in[2];
    const float* W = (const float*)d_in[3];
    const float* table = (const float*)d_in[4];
    float* out = (float*)d_out;

    const size_t nW = (size_t)HIDDEN * IN_DIM;   // 884,736 halves = 1.77 MB
    if (ws_size >= nW * sizeof(_Float16)) {
        _Float16* Wp = (_Float16*)d_ws;
        pack_w<<<432, 256, 0, stream>>>(W, Wp);
        gemm_pe<<<M_TOTAL / BM, 512, 0, stream>>>(pixel, Wp, pos, pad, table, out);
    } else {
        long total = (long)M_TOTAL * HIDDEN;
        fallback_naive<<<(int)((total + 255) / 256), 256, 0, stream>>>(pixel, W, pos, pad,
                                                                       table, out);
    }
}

// Round 7
// 564.126 us; speedup vs baseline: 1.9927x; 1.0593x over previous
//
#include <hip/hip_runtime.h>

#define HIDDEN 1152
#define IN_DIM 768
#define POS_SIZE 64
#define M_TOTAL (16 * 4096)

#define BM 64
#define NPASS 3            /* passes of 384 cols (48 per wave) */
#define NSTAGE 24          /* K-stages per pass, K-depth 32 each */
#define TOTSTAGE (NPASS * NSTAGE)   /* 72 */

typedef _Float16 f16x8 __attribute__((ext_vector_type(8)));
typedef float f32x4 __attribute__((ext_vector_type(4)));
typedef float f32x8v __attribute__((ext_vector_type(8)));

typedef __attribute__((address_space(1))) const void global_cv;
typedef __attribute__((address_space(3))) void lds_v;

__device__ __forceinline__ void async16(const void* g, void* l) {
    __builtin_amdgcn_global_load_lds((global_cv*)g, (lds_v*)l, 16, 0, 0);
}

// ---------------------------------------------------------------------------
// Pack W fp32 [1152][768] row-major -> f16, fragment-ordered (refcheck'd r2-r6):
//   chunk(n16, ks, lane) at 16B-chunk index n16*1536 + ks*64 + lane
//   holds Wh[n16*16 + (lane&15)][ks*32 + (lane>>4)*8 .. +8)
// ---------------------------------------------------------------------------
__global__ __launch_bounds__(256) void pack_w(const float* __restrict__ W,
                                              _Float16* __restrict__ Wp) {
    unsigned tid = blockIdx.x * 256 + threadIdx.x;   // 110592 = 1152*96
    unsigned n = tid / 96u;
    unsigned kc = tid - n * 96u;
    f32x8v x = *(const f32x8v*)(W + (size_t)n * IN_DIM + kc * 8u);
    f16x8 h = __builtin_convertvector(x, f16x8);
    unsigned c = (n >> 4) * 1536u + kc * 16u + (n & 15u);
    ((f16x8*)Wp)[c] = h;
}

// ---------------------------------------------------------------------------
// Fused GEMM+PE, barrier-free main loop, WIDE wave tiles (64 x 48).
// A (fp32) -> f16 LDS once, K-major XOR-swizzled (conflict-free, refcheck'd r5/r6).
// B: per-wave PRIVATE 2-slot LDS ring (3 KB slots), per-wave counted vmcnt(3).
// Per wave per stage (K=32): af[4] + bf[3] ds_reads -> 12 MFMA (0.58 KB/MFMA
// of LDS reads vs 1.25 in r6 -- LDS bandwidth was the binding pipe).
// ---------------------------------------------------------------------------
__global__ __launch_bounds__(512, 2) void gemm_pe(
    const float* __restrict__ A,        // [M, 768] fp32
    const _Float16* __restrict__ Wp,    // packed f16 fragments
    const int* __restrict__ pos,        // [M,2]
    const int* __restrict__ pad,        // [M]
    const float* __restrict__ table,    // [2,64,1152] fp32
    float* __restrict__ out) {          // [M,1152] fp32
    __shared__ __align__(16) _Float16 sA[6144 * 8];       // 98,304 B (K-major chunks)
    __shared__ __align__(16) _Float16 sB[8 * 2 * 1536];   // 49,152 B; total 147,456 B

    const int m0 = blockIdx.x * BM;
    const int t = threadIdx.x;
    const int lane = t & 63;
    const int w = t >> 6;               // wave 0..7: owns 48 cols per pass
    const int quad = lane >> 4;
    const int l15 = lane & 15;

    const f16x8* wp = (const f16x8*)Wp;
    _Float16* myB = &sB[w * 3072];      // private ring: 2 slots x 1536 halves

    // prologue: stages 0,1 in flight (slots 0,1); overlaps A staging
#pragma unroll
    for (int g = 0; g < 2; ++g)
#pragma unroll
        for (int j = 0; j < 3; ++j)
            async16(wp + (size_t)((w * 3 + j) * 1536 + g * 64 + lane),
                    myB + g * 1536 + j * 512);

    // hoist per-thread PE metadata: 16 output rows/thread, packed px|py<<8|pad<<16
    int meta[16];
#pragma unroll
    for (int mi = 0; mi < 4; mi++)
#pragma unroll
        for (int r = 0; r < 4; r++) {
            const int gm = m0 + mi * 16 + quad * 4 + r;
            int px = pos[gm * 2];
            int py = pos[gm * 2 + 1];
            px = px < 0 ? 0 : px;
            py = py < 0 ? 0 : py;
            meta[mi * 4 + r] = px | (py << 8) | ((pad[gm] ? 1 : 0) << 16);
        }

    // stage A: 64 x 768 fp32 -> f16, K-major chunks with XOR swizzle (r5/r6):
    // chunk(kc,row) = kc*64 + (row ^ ((kc&7)<<1)); holds A[m0+row][kc*8..+8)
    {
        const float* gA = A + (size_t)m0 * IN_DIM;
#pragma unroll 4
        for (int i = 0; i < 12; i++) {
            int c = t + i * 512;                 // 0..6143 (64 rows x 96 k-chunks)
            int row = c / 96;
            int kc = c - row * 96;
            f32x8v x = *(const f32x8v*)(gA + (size_t)row * IN_DIM + kc * 8);
            f16x8 h = __builtin_convertvector(x, f16x8);
            int chunk = kc * 64 + (row ^ ((kc & 7) << 1));
            *(f16x8*)&sA[(size_t)chunk * 8] = h;
        }
    }
    __syncthreads();   // the ONLY barrier: A resident (also drains prologue DMA)

    for (int pass = 0; pass < NPASS; pass++) {
        f32x4 acc[4][3];
#pragma unroll
        for (int mi = 0; mi < 4; mi++)
#pragma unroll
            for (int j = 0; j < 3; j++) acc[mi][j] = (f32x4)0.f;

        for (int s = 0; s < NSTAGE; s++) {
            const int g = pass * NSTAGE + s;
            // top-of-stage counted wait: DMA(g) complete, DMA(g+1) in flight.
            // (epilogue loads/stores in the queue are newer than DMA(g): safe,
            //  vmcnt(3) over-waits them only at the 2 pass boundaries)
            if (g < TOTSTAGE - 1) {
                asm volatile("s_waitcnt vmcnt(3)" ::: "memory");
            } else {
                asm volatile("s_waitcnt vmcnt(0)" ::: "memory");
            }

            const int slot = g & 1;
            f16x8 bf[3];
#pragma unroll
            for (int j = 0; j < 3; ++j)
                bf[j] = *(const f16x8*)&myB[slot * 1536 + j * 512 + lane * 8];

            f16x8 af[4];
#pragma unroll
            for (int mi = 0; mi < 4; mi++) {
                const int kc = s * 4 + quad;
                const int row = (l15 + mi * 16) ^ ((kc & 7) << 1);
                af[mi] = *(const f16x8*)&sA[(size_t)(kc * 64 + row) * 8];
            }

            // ring-2 reuse guard: slot(g) reads must land before DMA(g+2)
            // overwrites the same slot (same-wave program order + lgkmcnt(0))
            asm volatile("s_waitcnt lgkmcnt(0)" ::: "memory");
            if (g < TOTSTAGE - 2) {
                const int g2 = g + 2;
                const int p2 = g2 / NSTAGE;
                const int s2 = g2 - p2 * NSTAGE;
                const int slot2 = g2 & 1;
#pragma unroll
                for (int j = 0; j < 3; ++j)
                    async16(wp + (size_t)((p2 * 24 + w * 3 + j) * 1536 + s2 * 64 + lane),
                            myB + slot2 * 1536 + j * 512);
            }

            __builtin_amdgcn_s_setprio(1);
#pragma unroll
            for (int mi = 0; mi < 4; mi++)
#pragma unroll
                for (int j = 0; j < 3; j++)
                    acc[mi][j] = __builtin_amdgcn_mfma_f32_16x16x32_f16(af[mi], bf[j],
                                                                        acc[mi][j], 0, 0, 0);
            __builtin_amdgcn_s_setprio(0);
        }

        // epilogue: C/D layout col=l15, row=quad*4+r (refcheck'd r0/r2-r6)
#pragma unroll
        for (int mi = 0; mi < 4; mi++)
#pragma unroll
            for (int r = 0; r < 4; r++) {
                const int gm = m0 + mi * 16 + quad * 4 + r;
                const int mv = meta[mi * 4 + r];
                const int px = mv & 255;
                const int py = (mv >> 8) & 255;
                const int isPad = mv >> 16;
                float* orow = out + (size_t)gm * HIDDEN;
#pragma unroll
                for (int j = 0; j < 3; j++) {
                    const int gn = pass * 384 + w * 48 + j * 16 + l15;
                    float pe = isPad ? 0.f
                                     : (table[(size_t)px * HIDDEN + gn] +
                                        table[(size_t)(POS_SIZE + py) * HIDDEN + gn]);
                    orow[gn] = acc[mi][j][r] + pe;
                }
            }
    }
}

// ---------------- fp32 fallback (only if ws too small) ----------------
__global__ __launch_bounds__(256) void fallback_naive(const float* __restrict__ A,
                                                      const float* __restrict__ W,
                                                      const int* __restrict__ pos,
                                                      const int* __restrict__ pad,
                                                      const float* __restrict__ table,
                                                      float* __restrict__ out) {
    long idx = (long)blockIdx.x * 256 + threadIdx.x;
    const long total = (long)M_TOTAL * HIDDEN;
    if (idx >= total) return;
    int m = (int)(idx / HIDDEN);
    int n = (int)(idx - (long)m * HIDDEN);
    const float* a = A + (size_t)m * IN_DIM;
    const float* wv = W + (size_t)n * IN_DIM;
    float s = 0.f;
    for (int k = 0; k < IN_DIM; k++) s += a[k] * wv[k];
    int px = pos[m * 2]; if (px < 0) px = 0;
    int py = pos[m * 2 + 1]; if (py < 0) py = 0;
    float pe = pad[m] ? 0.f : (table[(size_t)px * HIDDEN + n] +
                               table[(size_t)(POS_SIZE + py) * HIDDEN + n]);
    out[idx] = s + pe;
}

extern "C" void kernel_launch(void* const* d_in, const int* in_sizes, int n_in,
                              void* d_out, int out_size, void* d_ws, size_t ws_size,
                              hipStream_t stream) {
    const float* pixel = (const float*)d_in[0];
    const int* pos = (const int*)d_in[1];
    const int* pad = (const int*)d_in[2];
    const float* W = (const float*)d_in[3];
    const float* table = (const float*)d_in[4];
    float* out = (float*)d_out;

    const size_t nW = (size_t)HIDDEN * IN_DIM;   // 884,736 halves = 1.77 MB
    if (ws_size >= nW * sizeof(_Float16)) {
        _Float16* Wp = (_Float16*)d_ws;
        pack_w<<<432, 256, 0, stream>>>(W, Wp);
        gemm_pe<<<M_TOTAL / BM, 512, 0, stream>>>(pixel, Wp, pos, pad, table, out);
    } else {
        long total = (long)M_TOTAL * HIDDEN;
        fallback_naive<<<(int)((total + 255) / 256), 256, 0, stream>>>(pixel, W, pos, pad,
                                                                       table, out);
    }
}